// Round 2
// baseline (320.766 us; speedup 1.0000x reference)
//
#include <hip/hip_runtime.h>

// Problem constants (from reference)
#define B_ROWS  32768
#define S_SAMP  16
#define NRELS   238
#define DIM     256
#define N_NODES 100000

typedef __attribute__((ext_vector_type(8))) short  short8;   // 8 x bf16 (4 VGPRs)
typedef __attribute__((ext_vector_type(4))) float  f32x4;    // MFMA accumulator

static __device__ __forceinline__ unsigned short f2bf(float f) {
    unsigned int u = __float_as_uint(f);
    u += 0x7FFFu + ((u >> 16) & 1u);   // round-to-nearest-even
    return (unsigned short)(u >> 16);
}
static __device__ __forceinline__ float bf2f(unsigned short u) {
    return __uint_as_float(((unsigned int)u) << 32 - 16);
}

// Kernel 1: Wb = bf16(W) (row-major [n][k] == MFMA B-frag layout) and
// RWTb = bf16(relation_weight^T) [238][256] (contiguous bf16 gather rows).
__global__ __launch_bounds__(256) void prep_kernel(const float* __restrict__ W,
                                                   const float* __restrict__ RW,
                                                   unsigned short* __restrict__ Wb,
                                                   unsigned short* __restrict__ RWTb) {
    int i = blockIdx.x * 256 + threadIdx.x;
    if (i < DIM * DIM) Wb[i] = f2bf(W[i]);
    if (i < NRELS * DIM) {
        int r = i >> 8;      // relation id
        int d = i & 255;     // output dim
        RWTb[i] = f2bf(RW[d * NRELS + r]);
    }
}

// Kernel 2: FT[r][n] = bf16( F[r][:] . W[n][:] )  for all 100000 nodes.
// 64-row M-tile per block (4 waves; each wave one 16-row m-tile x 16 n-tiles,
// K=256 in 8 steps of 32). A staged fp32->bf16 into LDS (row padded to 264
// ushorts -> free 2-way conflicts only). B frags straight from bf16 Wb in L2.
__global__ __launch_bounds__(256) void transform_kernel(const float* __restrict__ F,
                                                        const unsigned short* __restrict__ Wb,
                                                        unsigned short* __restrict__ FT) {
    __shared__ unsigned short Abuf[64][264];
    const int tid  = threadIdx.x;
    const int lane = tid & 63;
    const int wid  = tid >> 6;
    const int m0   = blockIdx.x * 64;

    // Stage 64x256 fp32 rows -> bf16 LDS tile. 16 float4 loads per thread,
    // coalesced (64 threads cover one 1KB row). Clamp rows past N_NODES.
#pragma unroll
    for (int j = 0; j < 16; ++j) {
        int fid = j * 256 + tid;            // float4 index in tile [0,4096)
        int r  = fid >> 6;
        int c4 = fid & 63;
        int gr = m0 + r;
        if (gr >= N_NODES) gr = N_NODES - 1;
        float4 v = *(const float4*)(F + (size_t)gr * DIM + c4 * 4);
        ushort4 p;
        p.x = f2bf(v.x); p.y = f2bf(v.y); p.z = f2bf(v.z); p.w = f2bf(v.w);
        *(ushort4*)&Abuf[r][c4 * 4] = p;
    }
    __syncthreads();

    const int mrow = wid * 16 + (lane & 15);
    const int quad = lane >> 4;

    f32x4 acc[16];
#pragma unroll
    for (int n = 0; n < 16; ++n) acc[n] = (f32x4){0.f, 0.f, 0.f, 0.f};

#pragma unroll
    for (int kk = 0; kk < 8; ++kk) {
        short8 af = *(const short8*)&Abuf[mrow][kk * 32 + quad * 8];
#pragma unroll
        for (int n = 0; n < 16; ++n) {
            short8 bf = *(const short8*)(Wb + (size_t)(n * 16 + (lane & 15)) * DIM
                                            + kk * 32 + quad * 8);
            acc[n] = __builtin_amdgcn_mfma_f32_16x16x32_bf16(af, bf, acc[n], 0, 0, 0);
        }
    }

    // Epilogue: D[row=(lane>>4)*4+i][col=lane&15] per n-tile -> bf16 FT.
    const int col0  = lane & 15;
    const int rbase = m0 + wid * 16 + quad * 4;
#pragma unroll
    for (int n = 0; n < 16; ++n) {
        const int col = n * 16 + col0;
#pragma unroll
        for (int i = 0; i < 4; ++i) {
            const int r = rbase + i;
            if (r < N_NODES) FT[(size_t)r * DIM + col] = f2bf(acc[n][i]);
        }
    }
}

// Kernel 3: one wave per output row. 16 bf16 FT-row gathers (512 B each) +
// 16 bf16 RWTb-row gathers, fp32 mean, add, ReLU, fp32 store.
__global__ __launch_bounds__(256) void aggregate_kernel(const int* __restrict__ nbr,
                                                        const int* __restrict__ rels,
                                                        const unsigned short* __restrict__ FT,
                                                        const unsigned short* __restrict__ RWTb,
                                                        float* __restrict__ out) {
    const int lane = threadIdx.x & 63;
    const int row  = __builtin_amdgcn_readfirstlane(blockIdx.x * 4 + (threadIdx.x >> 6));
    const int* nb = nbr  + row * S_SAMP;   // wave-uniform -> s_load
    const int* rl = rels + row * S_SAMP;

    float a0 = 0.f, a1 = 0.f, a2 = 0.f, a3 = 0.f;
#pragma unroll
    for (int s = 0; s < S_SAMP; ++s) {
        const int nid = nb[s];
        const int rid = rl[s];
        const ushort4 f = *(const ushort4*)(FT   + (size_t)nid * DIM + lane * 4);
        const ushort4 g = *(const ushort4*)(RWTb + (size_t)rid * DIM + lane * 4);
        a0 += bf2f(f.x) + bf2f(g.x);
        a1 += bf2f(f.y) + bf2f(g.y);
        a2 += bf2f(f.z) + bf2f(g.z);
        a3 += bf2f(f.w) + bf2f(g.w);
    }
    const float sc = 1.0f / 16.0f;
    float4 o;
    o.x = fmaxf(a0 * sc, 0.f);
    o.y = fmaxf(a1 * sc, 0.f);
    o.z = fmaxf(a2 * sc, 0.f);
    o.w = fmaxf(a3 * sc, 0.f);
    *(float4*)(out + (size_t)row * DIM + lane * 4) = o;
}

extern "C" void kernel_launch(void* const* d_in, const int* in_sizes, int n_in,
                              void* d_out, int out_size, void* d_ws, size_t ws_size,
                              hipStream_t stream) {
    const int*   neighbors = (const int*)d_in[0];
    const int*   relations = (const int*)d_in[1];
    const float* features  = (const float*)d_in[2];
    const float* weight    = (const float*)d_in[3];
    const float* relw      = (const float*)d_in[4];
    float* out = (float*)d_out;

    char* ws = (char*)d_ws;
    // ws layout (bytes): Wb  bf16 [256*256]     at 0       (131072)
    //                    RWTb bf16 [238*256]    at 131072  (121856)
    //                    FT  bf16 [100000*256]  at 253952  (51200000)  ~51.5 MB total
    unsigned short* Wb   = (unsigned short*)ws;
    unsigned short* RWTb = (unsigned short*)(ws + 131072);
    unsigned short* FT   = (unsigned short*)(ws + 253952);

    prep_kernel<<<256, 256, 0, stream>>>(weight, relw, Wb, RWTb);
    transform_kernel<<<(N_NODES + 63) / 64, 256, 0, stream>>>(features, Wb, FT);
    aggregate_kernel<<<B_ROWS / 4, 256, 0, stream>>>(neighbors, relations, FT, RWTb, out);
}

// Round 3
// 228.894 us; speedup vs baseline: 1.4014x; 1.4014x over previous
//
#include <hip/hip_runtime.h>

// Problem constants (from reference)
#define B_ROWS  32768
#define S_SAMP  16
#define NRELS   238
#define DIM     256
#define N_NODES 100000

typedef __attribute__((ext_vector_type(8))) short  short8;    // 8 x bf16 (4 VGPRs)
typedef __attribute__((ext_vector_type(8))) unsigned short ushort8;
typedef __attribute__((ext_vector_type(4))) float  f32x4;     // MFMA accumulator

static __device__ __forceinline__ unsigned short f2bf(float f) {
    unsigned int u = __float_as_uint(f);
    u += 0x7FFFu + ((u >> 16) & 1u);   // round-to-nearest-even
    return (unsigned short)(u >> 16);
}
static __device__ __forceinline__ float bf2f(unsigned short u) {
    return __uint_as_float(((unsigned int)u) << 16);
}

// Kernel 1: Wb = bf16(W) (row-major [n][k] == MFMA B-frag layout) and
// RWTb = bf16(relation_weight^T) [238][256] (contiguous bf16 gather rows).
__global__ __launch_bounds__(256) void prep_kernel(const float* __restrict__ W,
                                                   const float* __restrict__ RW,
                                                   unsigned short* __restrict__ Wb,
                                                   unsigned short* __restrict__ RWTb) {
    int i = blockIdx.x * 256 + threadIdx.x;
    if (i < DIM * DIM) Wb[i] = f2bf(W[i]);
    if (i < NRELS * DIM) {
        int r = i >> 8;      // relation id
        int d = i & 255;     // output dim
        RWTb[i] = f2bf(RW[d * NRELS + r]);
    }
}

// Kernel 2: FT = bf16(F @ W^T) for all nodes.
// 512 threads = 8 waves = (mg in {0,1}) x (ng in {0..3}).
// B-frags live in REGISTERS (4 n-tiles x 8 k-frags = 128 VGPRs/wave, loaded
// once from L2). A staged per 128-row tile into 64KB LDS (fp32->bf16, XOR
// swizzle on 16B granules so both staging writes and frag reads are 2-way max).
// Persistent grid-stride loop over 782 tiles: HBM-streaming bound.
__global__ __launch_bounds__(512, 2) void transform_kernel(const float* __restrict__ F,
                                                           const unsigned short* __restrict__ Wb,
                                                           unsigned short* __restrict__ FT) {
    __shared__ unsigned short As[128 * 256];   // 64 KB
    const int tid  = threadIdx.x;
    const int lane = tid & 63;
    const int wid  = tid >> 6;
    const int mg   = wid >> 2;      // 0..1  : 64-row half of the tile
    const int ng   = wid & 3;       // 0..3  : 64-col group
    const int col0 = lane & 15;
    const int quad = lane >> 4;

    // Preload B fragments for this wave's 4 n-tiles (all 8 k-frags).
    short8 Breg[4][8];
#pragma unroll
    for (int j = 0; j < 4; ++j) {
#pragma unroll
        for (int kk = 0; kk < 8; ++kk) {
            int n = ng * 4 + j;
            Breg[j][kk] = *(const short8*)(Wb + (size_t)(n * 16 + col0) * DIM
                                              + kk * 32 + quad * 8);
        }
    }

    const int nIter = (N_NODES + 127) / 128;   // 782
    for (int it = blockIdx.x; it < nIter; it += gridDim.x) {
        const int m0 = it * 128;
        // Stage 128 fp32 rows -> bf16 LDS, 16B granules XOR-swizzled by (row&7).
#pragma unroll
        for (int i = 0; i < 8; ++i) {
            int c = i * 512 + tid;          // granule id in tile [0,4096)
            int r = c >> 5;                 // tile row
            int g = c & 31;                 // granule within row
            int gr = m0 + r; if (gr >= N_NODES) gr = N_NODES - 1;
            const float* p = F + (size_t)gr * DIM + g * 8;
            float4 v0 = *(const float4*)p;
            float4 v1 = *(const float4*)(p + 4);
            ushort8 pk;
            pk[0] = f2bf(v0.x); pk[1] = f2bf(v0.y); pk[2] = f2bf(v0.z); pk[3] = f2bf(v0.w);
            pk[4] = f2bf(v1.x); pk[5] = f2bf(v1.y); pk[6] = f2bf(v1.z); pk[7] = f2bf(v1.w);
            int gs = g ^ (r & 7);
            *(ushort8*)&As[r * 256 + gs * 8] = pk;
        }
        __syncthreads();

#pragma unroll
        for (int mt = 0; mt < 4; ++mt) {
            const int mrow = mg * 64 + mt * 16 + col0;   // tile row of a-frag
            f32x4 acc[4];
#pragma unroll
            for (int j = 0; j < 4; ++j) acc[j] = (f32x4){0.f, 0.f, 0.f, 0.f};
#pragma unroll
            for (int kk = 0; kk < 8; ++kk) {
                int gs = (kk * 4 + quad) ^ (col0 & 7);   // (row&7)==(col0&7)
                short8 af = *(const short8*)&As[mrow * 256 + gs * 8];
#pragma unroll
                for (int j = 0; j < 4; ++j)
                    acc[j] = __builtin_amdgcn_mfma_f32_16x16x32_bf16(af, Breg[j][kk], acc[j], 0, 0, 0);
            }
            // Epilogue: D[row=quad*4+i][col=col0] per n-tile -> bf16 FT.
            const int rbase = m0 + mg * 64 + mt * 16 + quad * 4;
#pragma unroll
            for (int j = 0; j < 4; ++j) {
                int col = (ng * 4 + j) * 16 + col0;
#pragma unroll
                for (int i2 = 0; i2 < 4; ++i2) {
                    int r = rbase + i2;
                    if (r < N_NODES) FT[(size_t)r * DIM + col] = f2bf(acc[j][i2]);
                }
            }
        }
        __syncthreads();   // As reused next iteration
    }
}

// Kernel 3: one wave per output row; lanes 0-31 handle even samples, 32-63 odd.
// Each lane: 8 FT gathers + 8 rel gathers of 16B (8 dims), fp32 accumulate,
// cross-half combine via shfl_xor(32), fused mean+add+ReLU, fp32 store.
__global__ __launch_bounds__(256) void aggregate_kernel(const int* __restrict__ nbr,
                                                        const int* __restrict__ rels,
                                                        const unsigned short* __restrict__ FT,
                                                        const unsigned short* __restrict__ RWTb,
                                                        float* __restrict__ out) {
    const int tid  = threadIdx.x;
    const int lane = tid & 63;
    const int row  = __builtin_amdgcn_readfirstlane(blockIdx.x * 4 + (tid >> 6));
    const int half = lane >> 5;       // 0: even samples, 1: odd samples
    const int li   = lane & 31;       // dim group: dims [li*8, li*8+8)

    const int2* nb2 = (const int2*)(nbr  + row * S_SAMP);   // wave-uniform -> s_load
    const int2* rl2 = (const int2*)(rels + row * S_SAMP);

    float acc[8] = {0.f, 0.f, 0.f, 0.f, 0.f, 0.f, 0.f, 0.f};
#pragma unroll
    for (int t = 0; t < 8; ++t) {
        int2 nn = nb2[t];
        int2 rr = rl2[t];
        int nid = half ? nn.y : nn.x;
        int rid = half ? rr.y : rr.x;
        ushort8 f = *(const ushort8*)(FT   + (size_t)nid * DIM + li * 8);
        ushort8 g = *(const ushort8*)(RWTb + (size_t)rid * DIM + li * 8);
#pragma unroll
        for (int j = 0; j < 8; ++j) acc[j] += bf2f(f[j]) + bf2f(g[j]);
    }
#pragma unroll
    for (int j = 0; j < 8; ++j) acc[j] += __shfl_xor(acc[j], 32, 64);

    const float sc = 1.0f / 16.0f;
    float s0 = half ? acc[4] : acc[0];
    float s1 = half ? acc[5] : acc[1];
    float s2 = half ? acc[6] : acc[2];
    float s3 = half ? acc[7] : acc[3];
    float4 o;
    o.x = fmaxf(s0 * sc, 0.f);
    o.y = fmaxf(s1 * sc, 0.f);
    o.z = fmaxf(s2 * sc, 0.f);
    o.w = fmaxf(s3 * sc, 0.f);
    *(float4*)(out + (size_t)row * DIM + li * 8 + half * 4) = o;
}

extern "C" void kernel_launch(void* const* d_in, const int* in_sizes, int n_in,
                              void* d_out, int out_size, void* d_ws, size_t ws_size,
                              hipStream_t stream) {
    const int*   neighbors = (const int*)d_in[0];
    const int*   relations = (const int*)d_in[1];
    const float* features  = (const float*)d_in[2];
    const float* weight    = (const float*)d_in[3];
    const float* relw      = (const float*)d_in[4];
    float* out = (float*)d_out;

    char* ws = (char*)d_ws;
    // ws layout (bytes): Wb  bf16 [256*256]     at 0       (131072)
    //                    RWTb bf16 [238*256]    at 131072  (121856)
    //                    FT  bf16 [100000*256]  at 253952  (51200000)  ~51.5 MB total
    unsigned short* Wb   = (unsigned short*)ws;
    unsigned short* RWTb = (unsigned short*)(ws + 131072);
    unsigned short* FT   = (unsigned short*)(ws + 253952);

    prep_kernel<<<256, 256, 0, stream>>>(weight, relw, Wb, RWTb);
    transform_kernel<<<256, 512, 0, stream>>>(features, Wb, FT);
    aggregate_kernel<<<B_ROWS / 4, 256, 0, stream>>>(neighbors, relations, FT, RWTb, out);
}